// Round 3
// baseline (584.281 us; speedup 1.0000x reference)
//
#include <hip/hip_runtime.h>
#include <math.h>
#include <stdint.h>

// Problem constants
#define BB    32
#define CIN   64
#define HH    32
#define WW    32
#define COUT  128
#define PP    1024      // HH*WW
#define OTILE 8         // output channels per block
#define PTILE 256       // pixels per block (4 waves x 64 px)
#define GSTRIDE 20      // dwords per (o,c) group in workspace (80 B)

// inv_denom = 1/(2*1.5*0.025) = 13.3333, shift = 0.1*inv_denom = 1.3333
// Work in log2 domain: Z = z*log2(e).
static constexpr float SCALE    = 19.235933878519513f;   // inv_denom * log2(e)
static constexpr float SBITS    = 1.9235933878519513f;   // shift * log2(e)
static constexpr float M2N      = 0.26359713811572677f;  // 2^-SBITS = e^-shift
static constexpr float OUTSCALE = 2.7025482032898827e-05f; // ALPHA*R*ln2^2
static constexpr float ZCUT     = 5.0f;   // skip if all lanes Z < -5: residual ~1.4e-5 worst case, threshold 2e-3
static constexpr float INVSCALE = 0.051986038544710014f; // 1/SCALE

// order-preserving float->u32 map (no NaNs in data)
__device__ __forceinline__ uint32_t fkey(uint32_t b) {
    return b ^ (uint32_t)(((int32_t)b >> 31) | 0x80000000u);
}

// Pre-pass: per (o,c) group, sort the 9 thetas ascending; stuff original k into
// the 4 low mantissa bits (<=1.5e-5 value perturbation, negligible vs budget).
// ws layout per group (stride 20 dw): dw0-8 stuffed sorted floats, dw9-17 keys.
__global__ __launch_bounds__(256) void sort_theta_kernel(
    const float* __restrict__ theta, uint32_t* __restrict__ ws)
{
    int g = blockIdx.x * 256 + threadIdx.x;   // g = o*CIN + c, matches theta layout
    if (g >= COUT * CIN) return;
    const float* tg = theta + (size_t)g * 9;
    uint32_t sb[9], sk[9];
#pragma unroll
    for (int k = 0; k < 9; ++k) {
        uint32_t b = (__float_as_uint(tg[k]) & ~15u) | (uint32_t)k;
        sb[k] = b;
        sk[k] = fkey(b);
    }
    // insertion sort ascending by key
    for (int i = 1; i < 9; ++i) {
        uint32_t vb = sb[i], vk = sk[i];
        int j = i - 1;
        while (j >= 0 && sk[j] > vk) { sk[j+1] = sk[j]; sb[j+1] = sb[j]; --j; }
        sk[j+1] = vk; sb[j+1] = vb;
    }
    uint32_t* og = ws + (size_t)g * GSTRIDE;
#pragma unroll
    for (int j = 0; j < 9; ++j) og[j] = sb[j];
#pragma unroll
    for (int j = 0; j < 9; ++j) og[9 + j] = sk[j];
}

__global__ __launch_bounds__(256) void nlconv_kernel(
    const float* __restrict__ x,       // [B, CIN, 32, 32]
    const uint32_t* __restrict__ ws,   // sorted theta groups
    float* __restrict__ out)           // [B, COUT, 32, 32]
{
    // lane-private 9-float scratch so the body can index xi[k] with dynamic k
    // stride 9 dwords: lanes hit banks (9t+k)%32 -> 2 lanes/bank = free
    __shared__ float sxi[PTILE * 9];

    const int t  = threadIdx.x;
    const int b  = blockIdx.x;
    const int pt = blockIdx.y;
    const int ot = blockIdx.z;
    const int p  = pt * PTILE + t;
    const int py = p >> 5;
    const int px = p & 31;
    const int o0 = ot * OTILE;

    float* myx = sxi + t * 9;

    int   off[9];
    float msc[9];
#pragma unroll
    for (int dy = 0; dy < 3; ++dy) {
#pragma unroll
        for (int dx = 0; dx < 3; ++dx) {
            int yy = py + dy - 1;
            int xx = px + dx - 1;
            bool ok = (yy >= 0) && (yy < HH) && (xx >= 0) && (xx < WW);
            int yc = min(max(yy, 0), HH - 1);
            int xc = min(max(xx, 0), WW - 1);
            off[dy * 3 + dx] = yc * WW + xc;
            msc[dy * 3 + dx] = ok ? SCALE : 0.0f;   // pad -> xi = 0 (true padded value)
        }
    }

    const float* xb = x + (size_t)b * (CIN * PP);

    float acc[OTILE];
#pragma unroll
    for (int i = 0; i < OTILE; ++i) acc[i] = 0.0f;

    // prime pipeline (c = 0)
    float xi[9];
#pragma unroll
    for (int k = 0; k < 9; ++k) xi[k] = xb[off[k]] * msc[k];

    for (int c = 0; c < CIN; ++c) {
        // prefetch next channel's patch
        const float* xcn = xb + (size_t)min(c + 1, CIN - 1) * PP;
        float xn[9];
#pragma unroll
        for (int k = 0; k < 9; ++k) xn[k] = xcn[off[k]] * msc[k];

        // stash current patch for dynamic-k access (lane-private; no sync needed)
#pragma unroll
        for (int k = 0; k < 9; ++k) myx[k] = xi[k];

        // wave-max over 9 offsets x 64 lanes
        float m = xi[0];
#pragma unroll
        for (int k = 1; k < 9; ++k) m = fmaxf(m, xi[k]);
#pragma unroll
        for (int s = 32; s > 0; s >>= 1)
            m = fmaxf(m, __shfl_xor(m, s));

        const float cut = (m + ZCUT) * INVSCALE;
        const uint32_t ck =
            __builtin_amdgcn_readfirstlane(fkey(__float_as_uint(cut)));

        const uint32_t* gb0 = ws + (size_t)(o0 * CIN + c) * GSTRIDE;
#pragma unroll
        for (int o = 0; o < OTILE; ++o) {
            const uint32_t* gb = gb0 + (size_t)o * (CIN * GSTRIDE);
            // SALU count of active thetas (keys sorted ascending)
            int cnt = 0;
#pragma unroll
            for (int j = 0; j < 9; ++j) cnt += (gb[9 + j] < ck) ? 1 : 0;
            // runtime-bounded, unroll-disabled loop: bodies run exactly cnt times
#pragma unroll 1
            for (int j = 0; j < cnt; ++j) {
                uint32_t tb = gb[j];                       // s_load (uniform)
                int   k  = (int)(tb & 15u);                // stuffed k index
                float th = __uint_as_float(tb);
                float xik = myx[k];                        // ds_read, dynamic uniform k
                float Zr  = fmaf(th, -SCALE, xik);         // Z = (x - theta)*SCALE (log2 units)
                float Zc  = fminf(Zr, 60.0f);              // overflow clamp
                float E   = __builtin_amdgcn_exp2f(Zc);    // 2^Z
                float n1  = 1.0f + E;
                float n2  = fmaf(E, M2N, 1.0f);            // 1 + 2^(Z-S)
                float sp1 = __builtin_amdgcn_logf(n1);     // softplus(z)/ln2
                float sp2 = __builtin_amdgcn_logf(n2);     // softplus(z-s)/ln2
                float tv  = (sp1 - sp2) * (sp1 + sp2);     // sp1^2 - sp2^2
                float tL  = fmaf(2.0f * SBITS, Zr, -SBITS * SBITS); // exact linear tail
                tv = (Zr > 24.0f) ? tL : tv;
                acc[o] += tv;
            }
        }

#pragma unroll
        for (int k = 0; k < 9; ++k) xi[k] = xn[k];
    }

    float* ob = out + ((size_t)b * COUT + o0) * PP + p;
#pragma unroll
    for (int o = 0; o < OTILE; ++o) {
        float v = acc[o] * OUTSCALE;
        v = fminf(fmaxf(v, 0.0f), 9.0f);
        ob[(size_t)o * PP] = v;
    }
}

extern "C" void kernel_launch(void* const* d_in, const int* in_sizes, int n_in,
                              void* d_out, int out_size, void* d_ws, size_t ws_size,
                              hipStream_t stream) {
    const float* x     = (const float*)d_in[0];  // [32,64,32,32]
    const float* theta = (const float*)d_in[1];  // [128,64,3,3]
    float* out         = (float*)d_out;          // [32,128,32,32]
    uint32_t* ws       = (uint32_t*)d_ws;        // 8192 groups x 80 B = 640 KB

    sort_theta_kernel<<<dim3((COUT * CIN + 255) / 256), dim3(256), 0, stream>>>(theta, ws);

    dim3 grid(BB, PP / PTILE, COUT / OTILE);     // 32 x 4 x 16 = 2048 blocks
    dim3 block(256);
    nlconv_kernel<<<grid, block, 0, stream>>>(x, ws, out);
}